// Round 2
// baseline (124.068 us; speedup 1.0000x reference)
//
#include <hip/hip_runtime.h>

// Shape fixed by reference setup_inputs()
constexpr int B = 4, H = 16, S = 4096, D = 128;
constexpr int BH = B * H;                 // 64 independent sequences
constexpr int ROWS_PER_BLOCK = 256;       // chunk length along S
constexpr int CHUNKS = S / ROWS_PER_BLOCK;// 16 chunks per sequence
constexpr int D4 = D / 4;                 // 32 float4 lanes cover D
constexpr int NBLK = BH * CHUNKS;         // 1024 blocks
constexpr int RPT = ROWS_PER_BLOCK / 8;   // 32 rows per thread (8 groups/block)

__device__ __forceinline__ float4 f4fma(float a, float4 x, float4 y) {
    float4 r;
    r.x = fmaf(a, x.x, y.x);
    r.y = fmaf(a, x.y, y.y);
    r.z = fmaf(a, x.z, y.z);
    r.w = fmaf(a, x.w, y.w);
    return r;
}

// Zero the lookback flags each call (ws is poisoned 0xAA once, never re-poisoned).
__global__ __launch_bounds__(256) void dc_init(unsigned* __restrict__ flags) {
    int t = blockIdx.x * 256 + threadIdx.x;
    if (t < NBLK) flags[t] = 0u;
}

// Single-pass discounted cumsum with decoupled lookback.
// Block bid = c*64 + bh  (chunk-0 blocks have the lowest IDs -> dispatched first).
// Thread (g = tid>>5, l = tid&31): rows [c*256 + g*32, +32), float4 column l.
__global__ __launch_bounds__(256, 2) void dc_scan(const float4* __restrict__ x,
                                                  const float* __restrict__ gamma,
                                                  float4* __restrict__ y,
                                                  float* aggf, float* incf,
                                                  unsigned* flags) {
    const int bid = blockIdx.x;
    const int c   = bid >> 6;
    const int bh  = bid & 63;
    const float gd = gamma[bh & (H - 1)];
    const int l = threadIdx.x & 31;
    const int g = threadIdx.x >> 5;

    // gamma^32 (5 squarings), gamma^256 (3 more)
    float g32 = gd;
    #pragma unroll
    for (int k = 0; k < 5; ++k) g32 *= g32;
    float g256 = g32;
    #pragma unroll
    for (int k = 0; k < 3; ++k) g256 *= g256;

    const size_t base = ((size_t)bh * S + (size_t)c * ROWS_PER_BLOCK + g * RPT) * D4 + l;
    const float4* p = x + base;

    // Load 32 rows, compute local inclusive scan in registers.
    float4 v[RPT];
    float4 carry = make_float4(0.f, 0.f, 0.f, 0.f);
    #pragma unroll
    for (int i = 0; i < RPT; ++i) {
        float4 t = p[(size_t)i * D4];
        carry = f4fma(gd, carry, t);
        v[i] = carry;
    }

    __shared__ float4 carr[8][32];
    __shared__ float4 Pb[32];
    carr[g][l] = carry;
    __syncthreads();

    // Exclusive prefix over groups j<g (decay gamma^32 per group).
    float4 T = make_float4(0.f, 0.f, 0.f, 0.f);
    for (int j = 0; j < g; ++j) T = f4fma(g32, T, carr[j][l]);

    float4 P = make_float4(0.f, 0.f, 0.f, 0.f);
    if (g == 0) {
        // Block aggregate over all 8 groups.
        float4 A = make_float4(0.f, 0.f, 0.f, 0.f);
        #pragma unroll
        for (int j = 0; j < 8; ++j) A = f4fma(g32, A, carr[j][l]);

        float* ag = aggf + (size_t)bid * D + l * 4;
        float* ic = incf + (size_t)bid * D + l * 4;

        if (c == 0) {
            // P = 0, inclusive prefix = A. Publish directly as PREFIX.
            __hip_atomic_store(ic + 0, A.x, __ATOMIC_RELAXED, __HIP_MEMORY_SCOPE_AGENT);
            __hip_atomic_store(ic + 1, A.y, __ATOMIC_RELAXED, __HIP_MEMORY_SCOPE_AGENT);
            __hip_atomic_store(ic + 2, A.z, __ATOMIC_RELAXED, __HIP_MEMORY_SCOPE_AGENT);
            __hip_atomic_store(ic + 3, A.w, __ATOMIC_RELAXED, __HIP_MEMORY_SCOPE_AGENT);
            if (l == 0)
                __hip_atomic_store(&flags[bid], 2u, __ATOMIC_RELEASE, __HIP_MEMORY_SCOPE_AGENT);
        } else {
            if (c < CHUNKS - 1) {
                // Publish aggregate early so successors can proceed.
                __hip_atomic_store(ag + 0, A.x, __ATOMIC_RELAXED, __HIP_MEMORY_SCOPE_AGENT);
                __hip_atomic_store(ag + 1, A.y, __ATOMIC_RELAXED, __HIP_MEMORY_SCOPE_AGENT);
                __hip_atomic_store(ag + 2, A.z, __ATOMIC_RELAXED, __HIP_MEMORY_SCOPE_AGENT);
                __hip_atomic_store(ag + 3, A.w, __ATOMIC_RELAXED, __HIP_MEMORY_SCOPE_AGENT);
                if (l == 0)
                    __hip_atomic_store(&flags[bid], 1u, __ATOMIC_RELEASE, __HIP_MEMORY_SCOPE_AGENT);
            }
            // Decoupled lookback: P = sum_{j<c} g256^(c-1-j) * A_j, short-circuit on PREFIX.
            float4 acc = make_float4(0.f, 0.f, 0.f, 0.f);
            float mult = 1.f;
            int j = c - 1;
            while (j >= 0) {
                const int jidx = (j << 6) | bh;
                unsigned f = __hip_atomic_load(&flags[jidx], __ATOMIC_ACQUIRE, __HIP_MEMORY_SCOPE_AGENT);
                f = __shfl(f, 0);
                while (f == 0u) {
                    __builtin_amdgcn_s_sleep(2);
                    f = __hip_atomic_load(&flags[jidx], __ATOMIC_ACQUIRE, __HIP_MEMORY_SCOPE_AGENT);
                    f = __shfl(f, 0);
                }
                const float* sp = ((f == 2u) ? incf : aggf) + (size_t)jidx * D + l * 4;
                float4 Av;
                Av.x = __hip_atomic_load(sp + 0, __ATOMIC_RELAXED, __HIP_MEMORY_SCOPE_AGENT);
                Av.y = __hip_atomic_load(sp + 1, __ATOMIC_RELAXED, __HIP_MEMORY_SCOPE_AGENT);
                Av.z = __hip_atomic_load(sp + 2, __ATOMIC_RELAXED, __HIP_MEMORY_SCOPE_AGENT);
                Av.w = __hip_atomic_load(sp + 3, __ATOMIC_RELAXED, __HIP_MEMORY_SCOPE_AGENT);
                acc = f4fma(mult, Av, acc);
                if (f == 2u) break;
                mult *= g256;
                --j;
            }
            P = acc;
            if (c < CHUNKS - 1) {
                float4 I = f4fma(g256, P, A);   // inclusive prefix of this chunk
                __hip_atomic_store(ic + 0, I.x, __ATOMIC_RELAXED, __HIP_MEMORY_SCOPE_AGENT);
                __hip_atomic_store(ic + 1, I.y, __ATOMIC_RELAXED, __HIP_MEMORY_SCOPE_AGENT);
                __hip_atomic_store(ic + 2, I.z, __ATOMIC_RELAXED, __HIP_MEMORY_SCOPE_AGENT);
                __hip_atomic_store(ic + 3, I.w, __ATOMIC_RELAXED, __HIP_MEMORY_SCOPE_AGENT);
                if (l == 0)
                    __hip_atomic_store(&flags[bid], 2u, __ATOMIC_RELEASE, __HIP_MEMORY_SCOPE_AGENT);
            }
        }
        Pb[l] = P;
    }
    __syncthreads();
    P = Pb[l];

    // Thread seed: s = gamma^(32g) * P + T
    float m = 1.f;
    for (int j = 0; j < g; ++j) m *= g32;
    float4 s = f4fma(m, P, T);

    // y_i = local_scan_i + gamma^(i+1) * s
    float4* q = y + base;
    float pw = gd;
    #pragma unroll
    for (int i = 0; i < RPT; ++i) {
        float4 o = f4fma(pw, s, v[i]);
        q[(size_t)i * D4] = o;
        pw *= gd;
    }
}

extern "C" void kernel_launch(void* const* d_in, const int* in_sizes, int n_in,
                              void* d_out, int out_size, void* d_ws, size_t ws_size,
                              hipStream_t stream) {
    const float4* x     = (const float4*)d_in[0];
    const float*  gamma = (const float*)d_in[1];
    float4*       y     = (float4*)d_out;

    // ws layout: flags (4 KiB) | agg (NBLK*D floats, 512 KiB) | inc (512 KiB)
    unsigned* flags = (unsigned*)d_ws;
    float*    aggf  = (float*)((char*)d_ws + 4096);
    float*    incf  = aggf + (size_t)NBLK * D;

    dc_init<<<NBLK / 256, 256, 0, stream>>>(flags);
    dc_scan<<<NBLK, 256, 0, stream>>>(x, gamma, y, aggf, incf, flags);
}

// Round 3
// 78.030 us; speedup vs baseline: 1.5900x; 1.5900x over previous
//
#include <hip/hip_runtime.h>

// Shape fixed by reference setup_inputs()
constexpr int B = 4, H = 16, S = 4096, D = 128;
constexpr int BH = B * H;                  // 64 independent sequences
constexpr int CHUNKS = 64;                 // chunks along S
constexpr int L = S / CHUNKS;              // 64 rows per chunk
constexpr int D4 = D / 4;                  // 32 float4 lanes cover D
constexpr int UNITS = BH * CHUNKS;         // 4096 (bh, c) units
constexpr int THREADS = UNITS * D4;        // 131072
constexpr int NBLK = THREADS / 256;        // 512 blocks

__device__ __forceinline__ float4 f4fma(float a, float4 x, float4 y) {
    float4 r;
    r.x = fmaf(a, x.x, y.x);
    r.y = fmaf(a, x.y, y.y);
    r.z = fmaf(a, x.z, y.z);
    r.w = fmaf(a, x.w, y.w);
    return r;
}

// ---------------------------------------------------------------------------
// Kernel 1: per-chunk carry  c_j[d] = sum_{i<L} gamma^{L-1-i} x[jL+i, d]
// Thread owns one (bh, c, l) float4 column; streams 64 rows.
// ---------------------------------------------------------------------------
__global__ __launch_bounds__(256) void dc_carry(const float4* __restrict__ x,
                                                const float* __restrict__ gamma,
                                                float4* __restrict__ carries) {
    const int tid  = blockIdx.x * 256 + threadIdx.x;
    const int l    = tid & (D4 - 1);
    const int unit = tid >> 5;            // (bh, c)
    const int c    = unit & (CHUNKS - 1);
    const int bh   = unit >> 6;
    const float g  = gamma[bh & (H - 1)];

    const float4* p = x + ((size_t)bh * S + (size_t)c * L) * D4 + l;
    float4 carry = make_float4(0.f, 0.f, 0.f, 0.f);
    #pragma unroll 8
    for (int i = 0; i < L; ++i) {
        carry = f4fma(g, carry, p[(size_t)i * D4]);
    }
    carries[(size_t)unit * D4 + l] = carry;
}

// ---------------------------------------------------------------------------
// Kernel 2: each unit redundantly reduces its predecessors' carries into the
// exclusive chunk prefix, then streams its 64 rows: run = g*run + x, store.
// No LDS, no barriers, no inter-block dependencies.
// ---------------------------------------------------------------------------
__global__ __launch_bounds__(256) void dc_scan(const float4* __restrict__ x,
                                               const float* __restrict__ gamma,
                                               const float4* __restrict__ carries,
                                               float4* __restrict__ y) {
    const int tid  = blockIdx.x * 256 + threadIdx.x;
    const int l    = tid & (D4 - 1);
    const int unit = tid >> 5;
    const int c    = unit & (CHUNKS - 1);
    const int bh   = unit >> 6;
    const float g  = gamma[bh & (H - 1)];

    // gamma^L = gamma^64 via 6 exact squarings
    float gL = g;
    #pragma unroll
    for (int k = 0; k < 6; ++k) gL *= gL;

    // Exclusive prefix over predecessor chunks: P = sum_{j<c} gL^{c-1-j} carry_j
    const float4* cp = carries + (size_t)(bh * CHUNKS) * D4 + l;
    float4 P = make_float4(0.f, 0.f, 0.f, 0.f);
    #pragma unroll 4
    for (int j = 0; j < c; ++j) {
        P = f4fma(gL, P, cp[(size_t)j * D4]);
    }

    // Stream the chunk with seed P: run = g*run + x_t  ->  y_t
    const size_t base = ((size_t)bh * S + (size_t)c * L) * D4 + l;
    const float4* p = x + base;
    float4*       q = y + base;
    float4 run = P;
    #pragma unroll 8
    for (int i = 0; i < L; ++i) {
        run = f4fma(g, run, p[(size_t)i * D4]);
        q[(size_t)i * D4] = run;
    }
}

extern "C" void kernel_launch(void* const* d_in, const int* in_sizes, int n_in,
                              void* d_out, int out_size, void* d_ws, size_t ws_size,
                              hipStream_t stream) {
    const float4* x     = (const float4*)d_in[0];
    const float*  gamma = (const float*)d_in[1];
    float4*       y     = (float4*)d_out;
    float4*       carries = (float4*)d_ws;   // UNITS * D floats = 2 MiB

    dc_carry<<<NBLK, 256, 0, stream>>>(x, gamma, carries);
    dc_scan<<<NBLK, 256, 0, stream>>>(x, gamma, carries, y);
}

// Round 4
// 75.714 us; speedup vs baseline: 1.6386x; 1.0306x over previous
//
#include <hip/hip_runtime.h>

// Shape fixed by reference setup_inputs()
constexpr int B = 4, H = 16, S = 4096, D = 128;
constexpr int BH = B * H;                  // 64 independent sequences
constexpr int CHUNKS = 128;                // chunks along S
constexpr int L = S / CHUNKS;              // 32 rows per chunk
constexpr int D4 = D / 4;                  // 32 float4 lanes cover D
constexpr int UNITS = BH * CHUNKS;         // 8192 (bh, c) units
constexpr int THREADS = UNITS * D4;        // 262144
constexpr int NBLK = THREADS / 256;        // 1024 blocks -> 4 blocks/CU

__device__ __forceinline__ float4 f4fma(float a, float4 x, float4 y) {
    float4 r;
    r.x = fmaf(a, x.x, y.x);
    r.y = fmaf(a, x.y, y.y);
    r.z = fmaf(a, x.z, y.z);
    r.w = fmaf(a, x.w, y.w);
    return r;
}

// ---------------------------------------------------------------------------
// Kernel 1: per-chunk carry  A_c[d] = sum_{i<L} gamma^{L-1-i} x[cL+i, d]
// ---------------------------------------------------------------------------
__global__ __launch_bounds__(256) void dc_carry(const float4* __restrict__ x,
                                                const float* __restrict__ gamma,
                                                float4* __restrict__ carries) {
    const int tid  = blockIdx.x * 256 + threadIdx.x;
    const int l    = tid & (D4 - 1);
    const int unit = tid >> 5;                 // (bh, c)
    const int bh   = unit >> 7;                // unit / CHUNKS
    const float g  = gamma[bh & (H - 1)];

    const float4* p = x + (size_t)unit * (L * D4) + l;   // units tile S contiguously
    float4 carry = make_float4(0.f, 0.f, 0.f, 0.f);
    #pragma unroll 8
    for (int i = 0; i < L; ++i) {
        carry = f4fma(g, carry, p[(size_t)i * D4]);
    }
    carries[(size_t)unit * D4 + l] = carry;
}

// ---------------------------------------------------------------------------
// Kernel 2: each unit redundantly reduces predecessor carries into its
// exclusive chunk prefix (4-way reassociated to shorten the serial chain),
// then streams its 32 rows: run = g*run + x  ->  y.
// ---------------------------------------------------------------------------
__global__ __launch_bounds__(256) void dc_scan(const float4* __restrict__ x,
                                               const float* __restrict__ gamma,
                                               const float4* __restrict__ carries,
                                               float4* __restrict__ y) {
    const int tid  = blockIdx.x * 256 + threadIdx.x;
    const int l    = tid & (D4 - 1);
    const int unit = tid >> 5;
    const int c    = unit & (CHUNKS - 1);
    const int bh   = unit >> 7;
    const float g  = gamma[bh & (H - 1)];

    // gamma^L = gamma^32 via 5 exact squarings; small powers for the 4-way walk
    float gL = g;
    #pragma unroll
    for (int k = 0; k < 5; ++k) gL *= gL;
    const float gL2 = gL * gL;
    const float gL3 = gL2 * gL;
    const float gL4 = gL2 * gL2;

    // Exclusive prefix over predecessors: P = sum_{j<c} gL^{c-1-j} A_j
    const float4* cp = carries + (size_t)(bh * CHUNKS) * D4 + l;
    float4 P = make_float4(0.f, 0.f, 0.f, 0.f);
    int j = 0;
    for (; j + 4 <= c; j += 4) {
        float4 a0 = cp[(size_t)(j + 0) * D4];
        float4 a1 = cp[(size_t)(j + 1) * D4];
        float4 a2 = cp[(size_t)(j + 2) * D4];
        float4 a3 = cp[(size_t)(j + 3) * D4];
        float4 t = f4fma(gL, a2, a3);      // gL*a2 + a3
        t = f4fma(gL2, a1, t);             // + gL^2*a1
        t = f4fma(gL3, a0, t);             // + gL^3*a0  (off the P-chain)
        P = f4fma(gL4, P, t);              // 1 chain-FMA per 4 carries
    }
    for (; j < c; ++j) {
        P = f4fma(gL, P, cp[(size_t)j * D4]);
    }

    // Stream the chunk with seed P
    const size_t base = (size_t)unit * (L * D4) + l;
    const float4* p = x + base;
    float4*       q = y + base;
    float4 run = P;
    #pragma unroll 8
    for (int i = 0; i < L; ++i) {
        run = f4fma(g, run, p[(size_t)i * D4]);
        q[(size_t)i * D4] = run;
    }
}

extern "C" void kernel_launch(void* const* d_in, const int* in_sizes, int n_in,
                              void* d_out, int out_size, void* d_ws, size_t ws_size,
                              hipStream_t stream) {
    const float4* x     = (const float4*)d_in[0];
    const float*  gamma = (const float*)d_in[1];
    float4*       y     = (float4*)d_out;
    float4*       carries = (float4*)d_ws;   // UNITS * D floats = 4 MiB

    dc_carry<<<NBLK, 256, 0, stream>>>(x, gamma, carries);
    dc_scan<<<NBLK, 256, 0, stream>>>(x, gamma, carries, y);
}

// Round 5
// 72.310 us; speedup vs baseline: 1.7158x; 1.0471x over previous
//
#include <hip/hip_runtime.h>

// Shape fixed by reference setup_inputs()
constexpr int B = 4, H = 16, S = 4096, D = 128;
constexpr int BH = B * H;                  // 64 independent sequences
constexpr int CHUNKS = 128;                // chunks along S
constexpr int L = S / CHUNKS;              // 32 rows per chunk
constexpr int D4 = D / 4;                  // 32 float4 lanes cover D
constexpr int UNITS = BH * CHUNKS;         // 8192 (bh, c) units
constexpr int THREADS = UNITS * D4;        // 262144
constexpr int NBLK = THREADS / 256;        // 1024 blocks -> 4 blocks/CU

typedef float f32x4 __attribute__((ext_vector_type(4)));

__device__ __forceinline__ float4 f4fma(float a, float4 x, float4 y) {
    float4 r;
    r.x = fmaf(a, x.x, y.x);
    r.y = fmaf(a, x.y, y.y);
    r.z = fmaf(a, x.z, y.z);
    r.w = fmaf(a, x.w, y.w);
    return r;
}

// Non-temporal float4 store: y is written once and never re-read this launch;
// the nt hint keeps the write stream from evicting x out of L2/L3.
__device__ __forceinline__ void nt_store4(float4* p, float4 v) {
    union { float4 s; f32x4 v4; } u;
    u.s = v;
    __builtin_nontemporal_store(u.v4, (f32x4*)p);
}

// ---------------------------------------------------------------------------
// Kernel 1: per-chunk carry  A_c[d] = sum_{i<L} gamma^{L-1-i} x[cL+i, d]
// Regular loads: we WANT x to land in L3 for kernel 2's re-read.
// ---------------------------------------------------------------------------
__global__ __launch_bounds__(256) void dc_carry(const float4* __restrict__ x,
                                                const float* __restrict__ gamma,
                                                float4* __restrict__ carries) {
    const int tid  = blockIdx.x * 256 + threadIdx.x;
    const int l    = tid & (D4 - 1);
    const int unit = tid >> 5;                 // (bh, c)
    const int bh   = unit >> 7;                // unit / CHUNKS
    const float g  = gamma[bh & (H - 1)];

    const float4* p = x + (size_t)unit * (L * D4) + l;   // units tile S contiguously
    float4 carry = make_float4(0.f, 0.f, 0.f, 0.f);
    #pragma unroll 8
    for (int i = 0; i < L; ++i) {
        carry = f4fma(g, carry, p[(size_t)i * D4]);
    }
    carries[(size_t)unit * D4 + l] = carry;   // regular store: K2 re-reads these
}

// ---------------------------------------------------------------------------
// Kernel 2: redundant predecessor-carry reduction (4-way reassociated) ->
// exclusive chunk prefix, then stream 32 rows: run = g*run + x -> y (nt).
// ---------------------------------------------------------------------------
__global__ __launch_bounds__(256) void dc_scan(const float4* __restrict__ x,
                                               const float* __restrict__ gamma,
                                               const float4* __restrict__ carries,
                                               float4* __restrict__ y) {
    const int tid  = blockIdx.x * 256 + threadIdx.x;
    const int l    = tid & (D4 - 1);
    const int unit = tid >> 5;
    const int c    = unit & (CHUNKS - 1);
    const int bh   = unit >> 7;
    const float g  = gamma[bh & (H - 1)];

    // gamma^L = gamma^32 via 5 exact squarings; small powers for the 4-way walk
    float gL = g;
    #pragma unroll
    for (int k = 0; k < 5; ++k) gL *= gL;
    const float gL2 = gL * gL;
    const float gL3 = gL2 * gL;
    const float gL4 = gL2 * gL2;

    const size_t base = (size_t)unit * (L * D4) + l;
    const float4* p = x + base;
    float4*       q = y + base;

    // Prefetch the first 4 x rows so the stream overlaps the carry walk.
    float4 v0 = p[0 * D4];
    float4 v1 = p[1 * D4];
    float4 v2 = p[2 * D4];
    float4 v3 = p[3 * D4];

    // Exclusive prefix over predecessors: P = sum_{j<c} gL^{c-1-j} A_j
    const float4* cp = carries + (size_t)(bh * CHUNKS) * D4 + l;
    float4 P = make_float4(0.f, 0.f, 0.f, 0.f);
    int j = 0;
    for (; j + 4 <= c; j += 4) {
        float4 a0 = cp[(size_t)(j + 0) * D4];
        float4 a1 = cp[(size_t)(j + 1) * D4];
        float4 a2 = cp[(size_t)(j + 2) * D4];
        float4 a3 = cp[(size_t)(j + 3) * D4];
        float4 t = f4fma(gL, a2, a3);      // gL*a2 + a3
        t = f4fma(gL2, a1, t);             // + gL^2*a1
        t = f4fma(gL3, a0, t);             // + gL^3*a0  (off the P-chain)
        P = f4fma(gL4, P, t);              // 1 chain-FMA per 4 carries
    }
    for (; j < c; ++j) {
        P = f4fma(gL, P, cp[(size_t)j * D4]);
    }

    // Stream the chunk with seed P
    float4 run = P;
    run = f4fma(g, run, v0); nt_store4(q + 0 * D4, run);
    run = f4fma(g, run, v1); nt_store4(q + 1 * D4, run);
    run = f4fma(g, run, v2); nt_store4(q + 2 * D4, run);
    run = f4fma(g, run, v3); nt_store4(q + 3 * D4, run);
    #pragma unroll 7
    for (int i = 4; i < L; ++i) {
        run = f4fma(g, run, p[(size_t)i * D4]);
        nt_store4(q + (size_t)i * D4, run);
    }
}

extern "C" void kernel_launch(void* const* d_in, const int* in_sizes, int n_in,
                              void* d_out, int out_size, void* d_ws, size_t ws_size,
                              hipStream_t stream) {
    const float4* x     = (const float4*)d_in[0];
    const float*  gamma = (const float*)d_in[1];
    float4*       y     = (float4*)d_out;
    float4*       carries = (float4*)d_ws;   // UNITS * D floats = 4 MiB

    dc_carry<<<NBLK, 256, 0, stream>>>(x, gamma, carries);
    dc_scan<<<NBLK, 256, 0, stream>>>(x, gamma, carries, y);
}